// Round 7
// baseline (412.734 us; speedup 1.0000x reference)
//
#include <hip/hip_runtime.h>
#include <math.h>

// Problem constants
#define B_ 32
#define C_ 512
#define G_ 32
#define N_ 1024          // H*W
#define OC3_ 1536        // 3*C
#define EPS_ 1e-5f

typedef __attribute__((ext_vector_type(8))) short short8;
typedef __attribute__((ext_vector_type(4))) float f32x4;

// fp32 -> bf16 RNE
__device__ inline unsigned short f2bf(float f) {
    unsigned u = __builtin_bit_cast(unsigned, f);
    u += 0x7fffu + ((u >> 16) & 1u);
    return (unsigned short)(u >> 16);
}
__device__ inline unsigned pack2(float lo, float hi) {
    return (unsigned)f2bf(lo) | ((unsigned)f2bf(hi) << 16);
}
__device__ inline float bf2f(unsigned short u) {
    return __builtin_bit_cast(float, ((unsigned)u) << 16);
}

// async global->LDS 16 B per lane (gfx950). LDS dest = wave-uniform base +
// lane*16; all call sites use base + tid*8 (shorts).
typedef const __attribute__((address_space(1))) unsigned int* gas_u32;
typedef __attribute__((address_space(3))) unsigned int* las_u32;
__device__ __forceinline__ void cp16(unsigned short* lds, const unsigned short* g) {
    __builtin_amdgcn_global_load_lds((gas_u32)g, (las_u32)lds, 16, 0, 0);
}

// Shared batch->XCD decomposition: 1-D grids decoded so bid%8 == bz%8 when
// nb%8==0 -- keeps each batch's inter-kernel buffers on one XCD L2.
__device__ __forceinline__ void xcd_decode(int bid, int nbpb, int nbz,
                                           int& bz, int& local) {
    if ((nbz & 7) == 0) {
        int xcd = bid & 7;
        int rest = bid >> 3;
        local = rest % nbpb;
        bz = (rest / nbpb) * 8 + xcd;
    } else {
        bz = bid / nbpb;
        local = bid % nbpb;
    }
}

// ---------------------------------------------------------------------------
// Merged prep. Blocks 0..1023: GroupNorm stats. Blocks 1024..2047: weight cvt.
// ---------------------------------------------------------------------------
__global__ __launch_bounds__(256) void prep_kernel(
    const float* __restrict__ x, float* __restrict__ stats,
    const float* __restrict__ qkv_w, unsigned short* __restrict__ wqkv,
    const float* __restrict__ proj_w, unsigned short* __restrict__ wproj)
{
    __shared__ float r1[256], r2[256];
    int bid = blockIdx.x;
    if (bid < 1024) {
        int bg = bid;
        const float4* xv = (const float4*)(x + (size_t)bg * 16 * N_);
        float s = 0.f, ss = 0.f;
        for (int i = threadIdx.x; i < 4096; i += 256) {
            float4 v = xv[i];
            s  += v.x + v.y + v.z + v.w;
            ss += v.x*v.x + v.y*v.y + v.z*v.z + v.w*v.w;
        }
        r1[threadIdx.x] = s; r2[threadIdx.x] = ss;
        __syncthreads();
        for (int off = 128; off > 0; off >>= 1) {
            if (threadIdx.x < off) {
                r1[threadIdx.x] += r1[threadIdx.x + off];
                r2[threadIdx.x] += r2[threadIdx.x + off];
            }
            __syncthreads();
        }
        if (threadIdx.x == 0) {
            float mean = r1[0] * (1.f / 16384.f);
            float var  = r2[0] * (1.f / 16384.f) - mean * mean;
            stats[bg * 2 + 0] = mean;
            stats[bg * 2 + 1] = rsqrtf(var + EPS_);
        }
    } else {
        int i = (bid - 1024) * 256 + threadIdx.x;   // float4 index
        const int nQ = OC3_ * C_ / 4;               // 196608
        float4 v;
        uint2 o;
        if (i < nQ) {
            v = ((const float4*)qkv_w)[i];
            o.x = pack2(v.x, v.y); o.y = pack2(v.z, v.w);
            ((uint2*)wqkv)[i] = o;
        } else {
            int j = i - nQ;                          // < 65536
            v = ((const float4*)proj_w)[j];
            o.x = pack2(v.x, v.y); o.y = pack2(v.z, v.w);
            ((uint2*)wproj)[j] = o;
        }
    }
}

// ---------------------------------------------------------------------------
// hhatT producer: x[b][c][n] fp32 -> GN affine -> hhatT[bz][n][c] bf16.
// ---------------------------------------------------------------------------
__global__ __launch_bounds__(256) void hhatT_kernel(
    const float* __restrict__ x, const float* __restrict__ stats,
    const float* __restrict__ nw, const float* __restrict__ nbias,
    unsigned short* __restrict__ hhatT, long sH, int b0, int nbz)
{
    int bz, local;
    xcd_decode(blockIdx.x, 128, nbz, bz, local);
    int b = b0 + bz;
    int nt = (local & 15) * 64, ct = (local >> 4) * 64;
    const float* xb = x + (size_t)b * C_ * N_;
    const float* st = stats + b * 2 * G_;

    __shared__ float T[64][65];
    int tid = threadIdx.x;

    #pragma unroll
    for (int p = 0; p < 4; ++p) {
        int c = p * 16 + (tid >> 4);
        int n4 = (tid & 15) * 4;
        float4 v = *(const float4*)&xb[(size_t)(ct + c) * N_ + nt + n4];
        int g = (ct + c) >> 4;
        float w0 = nw[ct + c] * st[g * 2 + 1];
        float bb = nbias[ct + c] - st[g * 2] * w0;
        T[c][n4]   = v.x * w0 + bb;
        T[c][n4+1] = v.y * w0 + bb;
        T[c][n4+2] = v.z * w0 + bb;
        T[c][n4+3] = v.w * w0 + bb;
    }
    __syncthreads();
    #pragma unroll
    for (int p = 0; p < 2; ++p) {
        int n  = p * 32 + (tid >> 3);
        int c8 = (tid & 7) * 8;
        short8 s;
        #pragma unroll
        for (int u = 0; u < 8; ++u) s[u] = (short)f2bf(T[c8 + u][n]);
        *(short8*)&hhatT[(size_t)bz * sH + (size_t)(nt + n) * C_ + ct + c8] = s;
    }
}

// ---------------------------------------------------------------------------
// R16: gemm8w -- 8-wave split-K 128x128 GEMM with counted vmcnt (T3/T4/T5).
//   D[row][col] = sum_k A[row][k]*B[col][k];  EPI 2: bf16*scale, 3: bf16.
//
// WHY: 7 structural variants all plateau at 560-620 TF with every pipe <30%.
// Guide regime-gate: counted-vmcnt/setprio pay ONLY with wave role diversity
// (m218b: +38-73% counted-vs-drain at 8-phase; null at 2-phase lockstep --
// matches our R10 null). This kernel manufactures role diversity cheaply:
// waves 0-3 accumulate K-half 0, waves 4-7 K-half 1 (same 2x2 quadrants,
// SAME verified tile/involution/frag addressing); the two groups read
// different buffers so their memory/MFMA phases offset; s_setprio(1) lets
// the CU scheduler favor MFMA-ready waves.
//
// Schedule: per K-half a 3-buffer ring (tile i in buf i%3), stage lead 2:
// interval i stages pair i+2 (1 cp16/thread per tile, 4/interval), then
// ds_read+MFMA tile i, then s_waitcnt vmcnt(4) + s_barrier. Ledger (in-order
// retirement, m135): at interval-i end, newest 4 = pair i+2 -> pair i+1
// landed. vmcnt(0) only at the two tail intervals. Overwrite: buf (i+2)%3
// last read as tile i-1, reads complete before its end barrier; stage issues
// after it. sched_barrier(0) after each barrier pins next ds_reads.
// LDS 96 KB (2 groups x 3 bufs x (A 8K + B 8K)) -> 1 block/CU, 8 waves.
// Epilogue: group-1 partials -> LDS fp32 merge -> group-0 acc; then the
// proven staged bf16 store (key q<<4, conflicts==0 measured R14/R15).
// ---------------------------------------------------------------------------
template<int EPI>
__global__ __launch_bounds__(512) void gemm8w(
    const unsigned short* __restrict__ A, long sA, int lda,
    const unsigned short* __restrict__ B, long sB, int ldb,
    unsigned short* __restrict__ D, long sD, int ldd,
    int K, float scale, int gx, int gy, int nbz)
{
    int bz, local;
    xcd_decode(blockIdx.x, gx * gy, nbz, bz, local);
    int bx = local % gx, by = local / gx;

    const unsigned short* Ab = A + (size_t)bz * sA + (size_t)bx * 128 * lda;
    const unsigned short* Bb = B + (size_t)bz * sB + (size_t)by * 128 * ldb;

    // shorts: A(g,j) at (g*3+j)*4096, B(g,j) at 24576+(g*3+j)*4096. 96 KB.
    __shared__ __align__(16) unsigned short smem[49152];

    int tid = threadIdx.x;
    int w = tid >> 6, lane = tid & 63;
    int lm = lane & 15, q = lane >> 4;
    int g = w >> 2;                         // K-half group
    int qd = w & 3;                         // output quadrant
    int wrow = (qd >> 1) * 64, wcol = (qd & 1) * 64;

    int H = K >> 6;                         // 32-k tiles per half

    f32x4 acc[4][4];
    #pragma unroll
    for (int i = 0; i < 4; ++i)
        #pragma unroll
        for (int j = 0; j < 4; ++j) acc[i][j] = (f32x4)(0.f);

    int srow = tid >> 2;                               // 0..127
    int skc  = (((tid & 3) ^ ((srow >> 1) & 3))) * 8;  // swizzled src chunk
    int fco  = (q ^ ((lm >> 1) & 3)) * 8;              // frag phys chunk
    int td8  = tid * 8;

    const unsigned short* aP0 = Ab + (size_t)srow * lda + skc;
    const unsigned short* bP0 = Bb + (size_t)srow * ldb + skc;
    const unsigned short* aP1 = aP0 + H * 32;          // K-half 1
    const unsigned short* bP1 = bP0 + H * 32;

    #define AT_(gg, jj) (smem + ((gg) * 3 + (jj)) * 4096)
    #define BT_(gg, jj) (smem + 24576 + ((gg) * 3 + (jj)) * 4096)

    // prologue: stage tile-pairs 0 and 1 (8 cp16/thread)
    cp16(AT_(0,0) + td8, aP0);      cp16(BT_(0,0) + td8, bP0);
    cp16(AT_(1,0) + td8, aP1);      cp16(BT_(1,0) + td8, bP1);
    cp16(AT_(0,1) + td8, aP0 + 32); cp16(BT_(0,1) + td8, bP0 + 32);
    cp16(AT_(1,1) + td8, aP1 + 32); cp16(BT_(1,1) + td8, bP1 + 32);
    asm volatile("s_waitcnt vmcnt(4)" ::: "memory");   // pair 0 landed
    __builtin_amdgcn_s_barrier();
    __builtin_amdgcn_sched_barrier(0);

    int jc = 0;                // i % 3
    int j2 = 2;                // (i+2) % 3
    for (int i = 0; i < H; ++i) {
        if (i + 2 < H) {
            int off = (i + 2) * 32;
            cp16(AT_(0, j2) + td8, aP0 + off);
            cp16(BT_(0, j2) + td8, bP0 + off);
            cp16(AT_(1, j2) + td8, aP1 + off);
            cp16(BT_(1, j2) + td8, bP1 + off);
        }
        const unsigned short* At = AT_(g, jc);
        const unsigned short* Bt = BT_(g, jc);
        short8 af[4], bf[4];
        #pragma unroll
        for (int ii = 0; ii < 4; ++ii)
            af[ii] = *(const short8*)&At[(wrow + ii * 16 + lm) * 32 + fco];
        #pragma unroll
        for (int jj = 0; jj < 4; ++jj)
            bf[jj] = *(const short8*)&Bt[(wcol + jj * 16 + lm) * 32 + fco];
        __builtin_amdgcn_s_setprio(1);
        #pragma unroll
        for (int ii = 0; ii < 4; ++ii)
            #pragma unroll
            for (int jj = 0; jj < 4; ++jj)
                acc[ii][jj] = __builtin_amdgcn_mfma_f32_16x16x32_bf16(
                    af[ii], bf[jj], acc[ii][jj], 0, 0, 0);
        __builtin_amdgcn_s_setprio(0);
        // gate: pair i+1 landed; keep pair i+2 (newest 4) in flight
        if (i + 2 < H) asm volatile("s_waitcnt vmcnt(4)" ::: "memory");
        else           asm volatile("s_waitcnt vmcnt(0)" ::: "memory");
        __builtin_amdgcn_s_barrier();
        __builtin_amdgcn_sched_barrier(0);
        jc = (jc == 2) ? 0 : jc + 1;
        j2 = (j2 == 2) ? 0 : j2 + 1;
    }
    // loop exits through vmcnt(0)+barrier: all DMA landed, all reads consumed

    // ---- merge group-1 partials into group-0, then staged coalesced store
    float* Ms = (float*)(smem + 16384) + qd * 4096;    // [64][64] per quadrant
    if (g == 1) {
        #pragma unroll
        for (int ii = 0; ii < 4; ++ii)
            #pragma unroll
            for (int jj = 0; jj < 4; ++jj)
                #pragma unroll
                for (int r = 0; r < 4; ++r)
                    Ms[(ii * 16 + q * 4 + r) * 64 + jj * 16 + lm] = acc[ii][jj][r];
    }
    __builtin_amdgcn_s_barrier();
    if (g == 0) {
        unsigned short* Ts = smem;                     // [128][128] bf16, 32 KB
        #pragma unroll
        for (int jj = 0; jj < 4; ++jj) {
            int lc = wcol + jj * 16 + lm;
            #pragma unroll
            for (int ii = 0; ii < 4; ++ii) {
                #pragma unroll
                for (int r = 0; r < 4; ++r) {
                    int lr = wrow + ii * 16 + q * 4 + r;
                    float v = acc[ii][jj][r] +
                              Ms[(ii * 16 + q * 4 + r) * 64 + jj * 16 + lm];
                    if constexpr (EPI == 2) v *= scale;
                    Ts[lr * 128 + (lc ^ (q << 4))] = f2bf(v);
                }
            }
        }
    }
    __builtin_amdgcn_s_barrier();
    unsigned short* Dp = D + (size_t)bz * sD + (size_t)(bx * 128) * ldd + by * 128;
    #pragma unroll
    for (int k = 0; k < 4; ++k) {
        int flat = k * 4096 + tid * 8;                 // shorts, 8-aligned
        int rr = flat >> 7, cc = flat & 127;
        // reader row-key = (rr>>2)&3 = (8k+w)&3 = w&3 (wave-uniform)
        short8 vv = *(const short8*)&smem[flat ^ ((w & 3) << 4)];
        *(short8*)&Dp[(size_t)rr * ldd + cc] = vv;
    }
    #undef AT_
    #undef BT_
}

// ---------------------------------------------------------------------------
// 128x128 GEMM, 4 waves, BK=64 (proven R15). Used for EPI4 and EPI5 only.
// EPI: 4 fp32 +bias[row]+aux (residual) | 5 fused qkv.
// ---------------------------------------------------------------------------
template<int EPI>
__global__ __launch_bounds__(256) void gemm128(
    const unsigned short* __restrict__ A, long sA, int lda,
    const unsigned short* __restrict__ B, long sB, int ldb,
    void* __restrict__ Dv, long sD, int ldd,
    const float* __restrict__ bias,
    const float* __restrict__ aux, long sAux,
    int K, float scale, int gx, int gy, int nbz)
{
    int bz, local;
    xcd_decode(blockIdx.x, gx * gy, nbz, bz, local);

    int bx, by;
    bool p2 = false;
    if constexpr (EPI == 5) {
        p2 = local >= 64;
        int li = p2 ? local - 64 : local;
        bx = p2 ? (li & 3) : (li & 7);
        by = p2 ? (li >> 2) : (li >> 3);
    } else {
        bx = local % gx;
        by = local / gx;
    }

    const unsigned short *Ab, *Bb;
    if constexpr (EPI == 5) {
        if (p2) {
            Ab = B + (size_t)(1024 + bx * 128) * ldb;
            Bb = A + (size_t)bz * sA + (size_t)by * 128 * lda;
        } else {
            Ab = A + (size_t)bz * sA + (size_t)bx * 128 * lda;
            Bb = B + (size_t)by * 128 * ldb;
        }
    } else {
        Ab = A + (size_t)bz * sA + (size_t)bx * 128 * lda;
        Bb = B + (size_t)bz * sB + (size_t)by * 128 * ldb;
    }

    __shared__ __align__(16) unsigned short smem[8][4096];

    int tid = threadIdx.x;
    int w = tid >> 6, lane = tid & 63;
    int lm = lane & 15, q = lane >> 4;
    int wrow = (w >> 1) * 64, wcol = (w & 1) * 64;

    f32x4 acc[4][4];
    #pragma unroll
    for (int i = 0; i < 4; ++i)
        #pragma unroll
        for (int j = 0; j < 4; ++j) acc[i][j] = (f32x4)(0.f);

    int srow = tid >> 2;
    int skc  = (((tid & 3) ^ ((tid >> 3) & 3))) * 8;
    int fco  = (q ^ ((lm >> 1) & 3)) * 8;

    const unsigned short* a0p = Ab + (size_t)srow        * lda + skc;
    const unsigned short* a1p = Ab + (size_t)(64 + srow) * lda + skc;
    const unsigned short* b0p = Bb + (size_t)srow        * ldb + skc;
    const unsigned short* b1p = Bb + (size_t)(64 + srow) * ldb + skc;

    cp16(&smem[0][tid * 8],        a0p);
    cp16(&smem[0][2048 + tid * 8], a1p);
    cp16(&smem[1][tid * 8],        a0p + 32);
    cp16(&smem[1][2048 + tid * 8], a1p + 32);
    cp16(&smem[4][tid * 8],        b0p);
    cp16(&smem[4][2048 + tid * 8], b1p);
    cp16(&smem[5][tid * 8],        b0p + 32);
    cp16(&smem[5][2048 + tid * 8], b1p + 32);

    int nIter = K >> 6;
    for (int it = 0; it < nIter; ++it) {
        int cur = it & 1;
        __syncthreads();
        if (it + 1 < nIter) {
            int off = (it + 1) * 64;
            int nxt = cur ^ 1;
            cp16(&smem[nxt * 2][tid * 8],            a0p + off);
            cp16(&smem[nxt * 2][2048 + tid * 8],     a1p + off);
            cp16(&smem[nxt * 2 + 1][tid * 8],        a0p + off + 32);
            cp16(&smem[nxt * 2 + 1][2048 + tid * 8], a1p + off + 32);
            cp16(&smem[4 + nxt * 2][tid * 8],            b0p + off);
            cp16(&smem[4 + nxt * 2][2048 + tid * 8],     b1p + off);
            cp16(&smem[4 + nxt * 2 + 1][tid * 8],        b0p + off + 32);
            cp16(&smem[4 + nxt * 2 + 1][2048 + tid * 8], b1p + off + 32);
        }
        #pragma unroll
        for (int s = 0; s < 2; ++s) {
            const unsigned short* As = smem[cur * 2 + s];
            const unsigned short* Bs = smem[4 + cur * 2 + s];
            short8 af[4], bf[4];
            #pragma unroll
            for (int i = 0; i < 4; ++i)
                af[i] = *(const short8*)&As[(wrow + i * 16 + lm) * 32 + fco];
            #pragma unroll
            for (int j = 0; j < 4; ++j)
                bf[j] = *(const short8*)&Bs[(wcol + j * 16 + lm) * 32 + fco];
            #pragma unroll
            for (int i = 0; i < 4; ++i)
                #pragma unroll
                for (int j = 0; j < 4; ++j)
                    acc[i][j] = __builtin_amdgcn_mfma_f32_16x16x32_bf16(
                        af[i], bf[j], acc[i][j], 0, 0, 0);
        }
    }

    __syncthreads();

    if constexpr (EPI != 4) {
        unsigned short* Ts = &smem[0][0];
        #pragma unroll
        for (int j = 0; j < 4; ++j) {
            int lc = wcol + j * 16 + lm;
            float cb = 0.f;
            if constexpr (EPI == 5) { if (!p2) cb = bias[by * 128 + lc]; }
            #pragma unroll
            for (int i = 0; i < 4; ++i) {
                #pragma unroll
                for (int r = 0; r < 4; ++r) {
                    int lr = wrow + i * 16 + q * 4 + r;
                    float vle = acc[i][j][r];
                    if constexpr (EPI == 5)
                        vle += p2 ? bias[1024 + bx * 128 + lr] : cb;
                    Ts[lr * 128 + (lc ^ (q << 4))] = f2bf(vle);
                }
            }
        }
        __syncthreads();
        size_t doff = 0;
        if constexpr (EPI == 5) { if (p2) doff = (size_t)(1u << 20); }
        unsigned short* Dp = (unsigned short*)Dv + doff +
            (size_t)bz * sD + (size_t)(bx * 128) * ldd + by * 128;
        #pragma unroll
        for (int k = 0; k < 8; ++k) {
            int flat = k * 2048 + tid * 8;
            int rr = flat >> 7, cc = flat & 127;
            short8 vv = *(const short8*)&Ts[flat ^ (w << 4)];
            *(short8*)&Dp[(size_t)rr * ldd + cc] = vv;
        }
    } else {
        float* Ts32 = (float*)&smem[0][0];
        float* Dp = (float*)Dv + (size_t)bz * sD + (size_t)(bx * 128) * ldd + by * 128;
        const float* Ap = aux + (size_t)bz * sAux + (size_t)(bx * 128) * ldd + by * 128;
        #pragma unroll
        for (int h = 0; h < 2; ++h) {
            if (h) __syncthreads();
            if ((w & 1) == h) {
                #pragma unroll
                for (int j = 0; j < 4; ++j) {
                    int lch = j * 16 + lm;
                    #pragma unroll
                    for (int i = 0; i < 4; ++i) {
                        #pragma unroll
                        for (int r = 0; r < 4; ++r) {
                            int lr = wrow + i * 16 + q * 4 + r;
                            int wkey = (lr >> 2) & 7;
                            Ts32[lr * 64 + (lch ^ (wkey << 3))] =
                                acc[i][j][r] + bias[bx * 128 + lr];
                        }
                    }
                }
            }
            __syncthreads();
            #pragma unroll
            for (int k = 0; k < 8; ++k) {
                int flat = k * 1024 + tid * 4;
                int rr = flat >> 6, cc = flat & 63;
                int key = (4 * k + w) & 7;
                f32x4 vv = *(const f32x4*)&Ts32[flat ^ (key << 3)];
                size_t go = (size_t)rr * ldd + h * 64 + cc;
                f32x4 av = *(const f32x4*)&Ap[go];
                *(f32x4*)&Dp[go] = vv + av;
            }
        }
    }
}

// ---------------------------------------------------------------------------
// Softmax: in-place on bf16 scores. R16: 16 rows/block (4 rows per wave,
// sequential) -> 64 blocks/batch instead of 256 (less dispatch ramp).
// ---------------------------------------------------------------------------
__global__ __launch_bounds__(256) void softmax_kernel(
    unsigned short* __restrict__ sc, long sSc, int nbz)
{
    int bz, local;
    xcd_decode(blockIdx.x, 64, nbz, bz, local);
    int wid = threadIdx.x >> 6;
    int lane = threadIdx.x & 63;
    int row0 = local * 16 + wid * 4;

    for (int rr = 0; rr < 4; ++rr) {
        unsigned short* p = sc + (size_t)bz * sSc + (size_t)(row0 + rr) * N_ + lane * 16;
        short8 s0 = *(const short8*)p;
        short8 s1 = *(const short8*)(p + 8);
        float v[16];
        #pragma unroll
        for (int i = 0; i < 8; ++i) {
            v[i]     = bf2f((unsigned short)s0[i]);
            v[8 + i] = bf2f((unsigned short)s1[i]);
        }
        float m = v[0];
        #pragma unroll
        for (int i = 1; i < 16; ++i) m = fmaxf(m, v[i]);
        #pragma unroll
        for (int off = 32; off > 0; off >>= 1) m = fmaxf(m, __shfl_xor(m, off, 64));

        float sum = 0.f;
        #pragma unroll
        for (int i = 0; i < 16; ++i) { v[i] = __expf(v[i] - m); sum += v[i]; }
        #pragma unroll
        for (int off = 32; off > 0; off >>= 1) sum += __shfl_xor(sum, off, 64);
        float inv = 1.f / sum;

        short8 o0, o1;
        #pragma unroll
        for (int i = 0; i < 8; ++i) {
            o0[i] = (short)f2bf(v[i] * inv);
            o1[i] = (short)f2bf(v[8 + i] * inv);
        }
        *(short8*)p = o0;
        *(short8*)(p + 8) = o1;
    }
}

// ---------------------------------------------------------------------------
extern "C" void kernel_launch(void* const* d_in, const int* in_sizes, int n_in,
                              void* d_out, int out_size, void* d_ws, size_t ws_size,
                              hipStream_t stream) {
    const float* x      = (const float*)d_in[0];
    const float* norm_w = (const float*)d_in[1];
    const float* norm_b = (const float*)d_in[2];
    const float* qkv_w  = (const float*)d_in[3];
    const float* qkv_b  = (const float*)d_in[4];
    const float* proj_w = (const float*)d_in[5];
    const float* proj_b = (const float*)d_in[6];
    float* out = (float*)d_out;

    // Fixed region: stats (8 KB) + bf16 weights (2 MB).
    char* ws = (char*)d_ws;
    float* stats = (float*)ws;
    unsigned short* wqkv  = (unsigned short*)(ws + 8192);   // 1536x512
    unsigned short* wproj = wqkv + (size_t)OC3_ * C_;       // 512x512
    char* base = (char*)(wproj + (size_t)C_ * C_);
    const size_t fixed = 8192 + (size_t)OC3_ * C_ * 2 + (size_t)C_ * C_ * 2;

    // Per-batch aliased region: 6 MB.
    //   [0,2M)  qkT bf16 [n][1024]
    //   [2,3M)  v bf16 [c][n]     (= qkT + (1<<20) shorts; EPI5 part 2)
    //   [3,4M)  hhatT bf16 [n][c] -> after GEMM2 reused as houtT bf16 [n][c]
    //   [4,6M)  sc bf16 [n][m]    -> softmax in-place -> attn
    const size_t REG = 6u << 20;
    const long RSH = (long)(REG / 2);         // region stride in shorts

    size_t avail = ws_size > fixed ? ws_size - fixed : 0;
    int chunk = (int)(avail / REG);
    if (chunk < 1) chunk = 1;
    if (chunk > B_) chunk = B_;

    prep_kernel<<<dim3(2048), dim3(256), 0, stream>>>(
        x, stats, qkv_w, wqkv, proj_w, wproj);

    const float scale = 0.044194173824159216f;  // 512^-0.5

    unsigned short* qkT   = (unsigned short*)base;
    unsigned short* vbuf  = (unsigned short*)(base + (2u << 20));
    unsigned short* hhatT = (unsigned short*)(base + (3u << 20));
    unsigned short* houtT = (unsigned short*)(base + (3u << 20)); // aliases hhatT
    unsigned short* sc    = (unsigned short*)(base + (4u << 20)); // scores/attn

    for (int b0 = 0; b0 < B_; b0 += chunk) {
        int nb = B_ - b0 < chunk ? B_ - b0 : chunk;

        hhatT_kernel<<<dim3(128 * nb), dim3(256), 0, stream>>>(
            x, stats, norm_w, norm_b, hhatT, RSH, b0, nb);

        // GEMM1 fused (EPI5): qkT[n][0:1024] (+bias[col]) AND v[c][n]
        // (+bias[1024+row]); 96 blocks/batch (64 qk + 32 v).
        gemm128<5><<<dim3(96 * nb), dim3(256), 0, stream>>>(
            hhatT, RSH, C_,  wqkv, 0, C_,
            qkT, RSH, 1024,  qkv_b, nullptr, 0, C_, 0.f, 96, 1, nb);

        // GEMM2 (gemm8w): sc[n][m] = bf16(scale * qkT[n][0:512].qkT[m][512:1024])
        gemm8w<2><<<dim3(8 * 8 * nb), dim3(512), 0, stream>>>(
            qkT, RSH, 1024,  qkT + 512, RSH, 1024,
            sc, RSH, N_,  C_, scale, 8, 8, nb);

        softmax_kernel<<<dim3(64 * nb), dim3(256), 0, stream>>>(sc, RSH, nb);

        // GEMM3 (gemm8w): houtT[n][c] = attn[n][:] . v[c][:]   (K = 1024)
        gemm8w<3><<<dim3(8 * 4 * nb), dim3(512), 0, stream>>>(
            sc, RSH, N_,  vbuf, RSH, N_,
            houtT, RSH, C_,  N_, 0.f, 8, 4, nb);

        // GEMM4: out[o][n] = pw[o][:] . houtT[n][:] + pb[o] + x[o][n]
        gemm128<4><<<dim3(4 * 8 * nb), dim3(256), 0, stream>>>(
            wproj, 0, C_,  houtT, RSH, C_,
            out + (size_t)b0 * C_ * N_, (long)C_ * N_, N_,
            proj_b, x + (size_t)b0 * C_ * N_, (long)C_ * N_, C_, 0.f, 4, 8, nb);
    }
}